// Round 14
// baseline (617.957 us; speedup 1.0000x reference)
//
#include <hip/hip_runtime.h>
#include <cstdint>
#include <cmath>

#define HH 32
#define WW 32
#define NPX 1024          // H*W
#define CIN 2048
#define CMID 512
#define NA 9
#define NBOX 9216         // NA*NPX
#define NWRD 144          // NBOX/64

typedef double f64x4 __attribute__((ext_vector_type(4)));

// Device-pass-only builtin resolution (host pass has no amdgcn builtins).
#if defined(__HIP_DEVICE_COMPILE__)
#if __has_builtin(__builtin_amdgcn_mfma_f64_16x16x4f64)
#define MFMA64(a, b, c) __builtin_amdgcn_mfma_f64_16x16x4f64((a), (b), (c), 0, 0, 0)
#elif __has_builtin(__builtin_amdgcn_mfma_f64_16x16x4_f64)
#define MFMA64(a, b, c) __builtin_amdgcn_mfma_f64_16x16x4_f64((a), (b), (c), 0, 0, 0)
#endif
#if __has_builtin(__builtin_amdgcn_global_load_lds)
#define HAVE_GLL 1
#endif
#endif

// ------------------------------------------------------------------
// K0: probe f64 MFMA semantics on-device (proven round-5 probe).
// ------------------------------------------------------------------
__global__ void k_probe(int* __restrict__ flag) {
#ifdef MFMA64
  const int lane = threadIdx.x & 63;
  const int q = lane >> 4, n16 = lane & 15;
  f64x4 z = {0.0, 0.0, 0.0, 0.0};
  f64x4 d1 = MFMA64((double)(n16 + 1), (n16 == 0) ? 1.0 : 0.0, z);
  f64x4 d2 = MFMA64(1.0, (double)(n16 + 1), z);
  bool ok0 = true, ok1 = true, ok2 = true, ok3 = true;
#pragma unroll
  for (int r = 0; r < 4; ++r) {
    const double rc = (double)(4 * q + r + 1);
    const double rs = (double)(q + 4 * r + 1);
    const double p1 = d1[r], p2 = d2[r];
    const double colv = 4.0 * (double)(n16 + 1);
    ok0 &= (p1 == ((n16 == 0) ? 4.0 * rc : 0.0)) && (p2 == colv);
    ok1 &= (p1 == ((n16 == 0) ? 4.0 * rs : 0.0)) && (p2 == colv);
    ok2 &= (p1 == ((4 * q + r == 0) ? colv : 0.0)) && (p2 == 4.0 * rc);
    ok3 &= (p1 == ((q + 4 * r == 0) ? colv : 0.0)) && (p2 == 4.0 * rs);
  }
  const unsigned long long full = ~0ull;
  int f = 0;
  if (__ballot(ok0) == full) f = 1;
  else if (__ballot(ok1) == full) f = 2;
  else if (__ballot(ok2) == full) f = 3;
  else if (__ballot(ok3) == full) f = 4;
  if (threadIdx.x == 0) *flag = f;
#else
  if (threadIdx.x == 0) *flag = 0;
#endif
}

// ------------------------------------------------------------------
// K1a: fp64-MFMA 3x3 conv (runs iff flag != 0).
// Round-13 structure (gll weights + 1 barrier/stage + XCD swizzle) with
// xs staged as fp32 (exact: inputs are fp32; cvt->f64 at fragment read).
// Rationale (r13 PMC): conv was LDS-read-bound (1.33MB/CU-stage @ ~112B/cyc
// = 11850cyc > 9216cyc MFMA). fp32 xs halves B-operand bytes -> 737KB ->
// 6580cyc < MFMA -> MFMA-bound. wsm padded to 5632 floats so LDS=54.8KB
// keeps residency at EXACTLY 2 blocks/CU (r12 lesson: 3 blocks thrash L2).
// ------------------------------------------------------------------
__global__ __launch_bounds__(256, 2) void k_conv3x3_mfma(
    const float* __restrict__ x, const float* __restrict__ wgt,
    double* __restrict__ partial, int chunk, int nblk,
    const int* __restrict__ flag) {
#ifdef MFMA64
  const int f = *flag;
  if (f == 0) return;
  const bool swp = (f >= 3);
  const bool contig = (f == 1) || (f == 3);

  __shared__ float xs[2][8 * 152];    // [buf][cc*152 + r*38 + lcol]  9728 B
  __shared__ float wsm[2][5632];      // [buf][oc_l*72 + cc*9 + tap] (4608 used; padded -> 2 blk/CU)
  const int tid = threadIdx.x;
  // XCD-aware bijective swizzle (nblk % 8 == 0 by construction)
  const int bid = blockIdx.x;
  const int cpx = nblk >> 3;
  const int swz = (bid & 7) * cpx + (bid >> 3);
  const int pxt = swz & 15;          // 0..15
  const int oct = (swz >> 4) & 7;    // 0..7
  const int cz  = swz >> 7;
  const int h0  = pxt * 2;
  const int oc0 = oct * 64;
  const int cbase = cz * chunk;

  const int wv   = tid >> 6;         // wave 0..3
  const int lane = tid & 63;
  const int q    = lane >> 4;        // lane quarter (k offset within K=4)
  const int n16  = lane & 15;

  f64x4 acc[4];
#pragma unroll
  for (int t = 0; t < 4; ++t) acc[t] = (f64x4){0.0, 0.0, 0.0, 0.0};

  float xreg[5];                      // x prefetch (static indices)

#ifdef HAVE_GLL
  int wsrc[5];
#pragma unroll
  for (int m = 0; m < 5; ++m) {
    const int k = wv + 4 * m;                  // chunk id (wave-uniform)
    const int fidx = k * 256 + lane * 4;       // linear float idx in stage
    const int oc_l = fidx / 72;
    const int rem  = fidx - oc_l * 72;
    wsrc[m] = (oc0 + oc_l) * 18432 + rem;
  }
#define WISSUE(P, C0)                                                          \
  _Pragma("unroll")                                                            \
  for (int m = 0; m < 5; ++m) {                                                \
    const int k = wv + 4 * m;                                                  \
    if (k < 18) {                                                              \
      __builtin_amdgcn_global_load_lds(                                        \
          (const __attribute__((address_space(1))) void*)(wgt + (size_t)wsrc[m] + (size_t)(C0) * 9), \
          (__attribute__((address_space(3))) void*)(&wsm[P][k * 256]),         \
          16, 0, 0);                                                           \
    }                                                                          \
  }
#define WCOMMIT(P)
#else
  float wreg[18];
#define WISSUE(P, C0)                                                          \
  _Pragma("unroll")                                                            \
  for (int k = 0; k < 18; ++k) {                                               \
    const int idx = tid + k * 256;                                             \
    const int oc_l = idx / 72, rem = idx - oc_l * 72;                          \
    wreg[k] = wgt[(size_t)(oc0 + oc_l) * 18432 + (size_t)(C0) * 9 + rem];      \
  }
#define WCOMMIT(P)                                                             \
  _Pragma("unroll")                                                            \
  for (int k = 0; k < 18; ++k) wsm[P][tid + k * 256] = wreg[k];
#endif

#define XLOAD(C0)                                                              \
  _Pragma("unroll")                                                            \
  for (int k = 0; k < 5; ++k) {                                                \
    const int idx = tid + k * 256;                                             \
    float v = 0.f;                                                             \
    if (idx < 1152) {                                                          \
      const int cc = idx / 144, rem = idx - cc * 144;                          \
      const int r = rem / 36, lcol = rem - r * 36;                             \
      const int grow = h0 - 1 + r, gcol = lcol - 1;                            \
      if ((unsigned)grow < 32u && (unsigned)gcol < 32u)                        \
        v = x[((size_t)((C0) + cc) << 10) + (grow << 5) + gcol];               \
    }                                                                          \
    xreg[k] = v;                                                               \
  }

#define XWRITE(P)                                                              \
  _Pragma("unroll")                                                            \
  for (int k = 0; k < 5; ++k) {                                                \
    const int idx = tid + k * 256;                                             \
    if (idx < 1152) {                                                          \
      const int cc = idx / 144, rem = idx - cc * 144;                          \
      const int r = rem / 36, lcol = rem - r * 36;                             \
      xs[P][cc * 152 + r * 38 + lcol] = xreg[k];                               \
    }                                                                          \
  }

  const int nst = chunk >> 3;
  WISSUE(0, cbase)
  XLOAD(cbase)
  XWRITE(0)                           // vmcnt drains here
  WCOMMIT(0)
  __syncthreads();

  for (int s = 0; s < nst; ++s) {
    const int p = s & 1;
    if (s + 1 < nst) {
      WISSUE(p ^ 1, cbase + (s + 1) * 8)
      XLOAD(cbase + (s + 1) * 8)
    }
    __builtin_amdgcn_sched_barrier(0);  // keep load-issue ahead of compute

    const float* xb  = &xs[p][q * 152 + n16];
    const float* wbq = &wsm[p][((wv << 4) + n16) * 72 + q * 9];

#define CONV_INNER(SWPV)                                                       \
    _Pragma("unroll")                                                          \
    for (int tap = 0; tap < 9; ++tap) {                                        \
      const int dy = tap / 3, dx = tap - 3 * (tap / 3);                        \
      _Pragma("unroll")                                                        \
      for (int ksg = 0; ksg < 2; ++ksg) {                                      \
        const double av = (double)wbq[ksg * 36 + tap];                         \
        const float* xq = xb + ksg * 608;    /* 4 ch * 152 */                  \
        _Pragma("unroll")                                                      \
        for (int t = 0; t < 4; ++t) {                                          \
          const double bv = (double)xq[((t >> 1) + dy) * 38 + (t & 1) * 16 + dx]; \
          if (SWPV) acc[t] = MFMA64(bv, av, acc[t]);                           \
          else      acc[t] = MFMA64(av, bv, acc[t]);                           \
        }                                                                      \
      }                                                                        \
    }

    if (swp) { CONV_INNER(true) } else { CONV_INNER(false) }
#undef CONV_INNER

    if (s + 1 < nst) {
      XWRITE(p ^ 1)                   // vmcnt already drained by compute span
      WCOMMIT(p ^ 1)
      __syncthreads();                // single barrier per stage
    }
  }
#undef WISSUE
#undef WCOMMIT
#undef XLOAD
#undef XWRITE
  // epilogue: col = n16 (px within 16-group); row = contig ? 4q+j : q+4j
  double* out = partial + (size_t)cz * (CMID * NPX);
#pragma unroll
  for (int t = 0; t < 4; ++t) {
    const int px = ((h0 + (t >> 1)) << 5) + ((t & 1) << 4) + n16;
#pragma unroll
    for (int j = 0; j < 4; ++j) {
      const int row = contig ? ((q << 2) + j) : (q + (j << 2));
      const int oc = oc0 + (wv << 4) + row;
      out[(size_t)oc * NPX + px] = acc[t][j];
    }
  }
#endif
}

// ------------------------------------------------------------------
// K1b: proven fp64 VALU conv (runs iff flag == 0). Flat grid, same decode.
// ------------------------------------------------------------------
__global__ __launch_bounds__(256) void k_conv3x3_valu(
    const float* __restrict__ x, const float* __restrict__ wgt,
    double* __restrict__ partial, int chunk, int nblk,
    const int* __restrict__ flag) {
  if (*flag != 0) return;
  __shared__ double xs[8][4][36];
  __shared__ double ws_s[8 * 9 * 66];
  const int tid = threadIdx.x;
  const int bid = blockIdx.x;
  const int cpx = nblk >> 3;
  const int swz = (bid & 7) * cpx + (bid >> 3);
  const int pxt = swz & 15;
  const int oct = (swz >> 4) & 7;
  const int cz  = swz >> 7;
  const int h0  = pxt * 2;
  const int oc0 = oct * 64;
  const int cbase = cz * chunk;

  const int g   = tid & 15;
  const int ty  = tid >> 4;
  const int r_p = g >> 3;
  const int gc  = (g & 7) * 4;

  double acc[4][4];
#pragma unroll
  for (int a = 0; a < 4; ++a)
#pragma unroll
    for (int b = 0; b < 4; ++b) acc[a][b] = 0.0;

  const int stages = chunk >> 3;
  for (int s = 0; s < stages; ++s) {
    const int c0 = cbase + s * 8;
    __syncthreads();
    for (int idx = tid; idx < 1152; idx += 256) {
      int cc = idx / 144, rem = idx - cc * 144;
      int r = rem / 36, lcol = rem - r * 36;
      int grow = h0 - 1 + r, gcol = lcol - 1;
      float v = 0.f;
      if ((unsigned)grow < 32u && (unsigned)gcol < 32u)
        v = x[((size_t)(c0 + cc) << 10) + (grow << 5) + gcol];
      xs[cc][r][lcol] = (double)v;
    }
    for (int idx = tid; idx < 4608; idx += 256) {
      int oc_l = idx / 72, rem = idx - oc_l * 72;
      int cc = rem / 9, t = rem - cc * 9;
      ws_s[(cc * 9 + t) * 66 + oc_l] =
          (double)wgt[(size_t)(oc0 + oc_l) * 18432 + (size_t)(c0 + cc) * 9 + t];
    }
    __syncthreads();
    for (int cc = 0; cc < 8; ++cc) {
      double xr[3][8];
#pragma unroll
      for (int dy = 0; dy < 3; ++dy) {
        const double* xp = &xs[cc][r_p + dy][gc];
#pragma unroll
        for (int k = 0; k < 8; ++k) xr[dy][k] = xp[k];
      }
#pragma unroll
      for (int t = 0; t < 9; ++t) {
        const int dy = t / 3, dx = t - dy * 3;
        const double* wp = &ws_s[(cc * 9 + t) * 66 + ty * 4];
        const double w0 = wp[0], w1 = wp[1], w2 = wp[2], w3 = wp[3];
#pragma unroll
        for (int i = 0; i < 4; ++i) {
          const double xv = xr[dy][i + dx];
          acc[0][i] += w0 * xv;
          acc[1][i] += w1 * xv;
          acc[2][i] += w2 * xv;
          acc[3][i] += w3 * xv;
        }
      }
    }
  }
  const int pxg = (h0 + r_p) * 32 + gc;
  double* out = partial + (size_t)cz * (CMID * NPX);
#pragma unroll
  for (int j = 0; j < 4; ++j)
#pragma unroll
    for (int i = 0; i < 4; ++i)
      out[(size_t)(oc0 + ty * 4 + j) * NPX + pxg + i] = acc[j][i];
}

// ------------------------------------------------------------------
// K2: reduce split-K partials (fixed order) + bias + ReLU (fp64)
// ------------------------------------------------------------------
__global__ void k_reduce(const double* __restrict__ partial,
                         const float* __restrict__ bias,
                         double* __restrict__ feat, int S) {
  int idx = blockIdx.x * 256 + threadIdx.x;   // < 512*1024
  double s = (double)bias[idx >> 10];
  for (int z = 0; z < S; ++z) s += partial[(size_t)z * (CMID * NPX) + idx];
  feat[idx] = fmax(s, 0.0);
}

// ------------------------------------------------------------------
// K3: 1x1 convs, 9 channels per block, LDS-staged weights.
// grid (4 px-blocks, 6 ch-groups), block 256.
// ------------------------------------------------------------------
__global__ __launch_bounds__(256) void k_1x1(
    const double* __restrict__ feat,
    const float* __restrict__ cls_w, const float* __restrict__ cls_b,
    const float* __restrict__ bbox_w, const float* __restrict__ bbox_b,
    double* __restrict__ logits) {
  __shared__ float wsh[9 * 512];
  const int px = blockIdx.x * 256 + threadIdx.x;
  const int cg = blockIdx.y;                 // 0..5
  for (int idx = threadIdx.x; idx < 9 * 512; idx += 256) {
    int j = idx >> 9, c = idx & 511;
    int ch = cg * 9 + j;
    wsh[idx] = (ch < 18) ? cls_w[(size_t)ch * 512 + c]
                         : bbox_w[(size_t)(ch - 18) * 512 + c];
  }
  __syncthreads();
  double acc[9];
#pragma unroll
  for (int j = 0; j < 9; ++j) acc[j] = 0.0;
  for (int c = 0; c < 512; ++c) {
    const double fv = feat[((size_t)c << 10) + px];
#pragma unroll
    for (int j = 0; j < 9; ++j)
      acc[j] += fv * (double)wsh[(j << 9) + c];
  }
#pragma unroll
  for (int j = 0; j < 9; ++j) {
    const int ch = cg * 9 + j;
    const float bias = (ch < 18) ? cls_b[ch] : bbox_b[ch - 18];
    logits[((size_t)ch << 10) + px] = acc[j] + (double)bias;
  }
}

// ------------------------------------------------------------------
// K4: scores (fp64 sigmoid) + box decode (fp64) + rank/keep zero-init
// ------------------------------------------------------------------
__global__ void k_score_box(const double* __restrict__ logits,
                            double* __restrict__ scores, double* __restrict__ boxes,
                            int* __restrict__ rank, int* __restrict__ keep) {
  int i = blockIdx.x * 256 + threadIdx.x;     // < 9216
  rank[i] = 0;
  keep[i] = 0;
  int pos = i / 9, a = i - pos * 9;
  const double* obj = logits;
  const double* dl  = logits + 18 * NPX;
  double l0 = obj[a * NPX + pos], l1 = obj[(9 + a) * NPX + pos];
  double delta = l1 - l0;
  scores[i] = 1.0 / (1.0 + exp(-delta));
  double d0 = dl[(a * 4 + 0) * NPX + pos], d1 = dl[(a * 4 + 1) * NPX + pos];
  double d2 = dl[(a * 4 + 2) * NPX + pos], d3 = dl[(a * 4 + 3) * NPX + pos];
  const double s_arr[3] = {8.0, 16.0, 32.0};
  const double r_arr[3] = {0.5, 1.0, 2.0};
  double sA = s_arr[a / 3], rA = r_arr[a % 3];
  double aw = (double)(float)(sA * sqrt(rA));
  double ah = (double)(float)(sA / sqrt(rA));
  double px_ = d0 * aw, py_ = d1 * ah;
  double pw = exp(d2) * aw, ph = exp(d3) * ah;
  boxes[i * 4 + 0] = px_ - 0.5 * pw;
  boxes[i * 4 + 1] = py_ - 0.5 * ph;
  boxes[i * 4 + 2] = px_ + 0.5 * pw;
  boxes[i * 4 + 3] = py_ + 0.5 * ph;
}

// ------------------------------------------------------------------
// K5: stable descending rank via O(N^2) count (int atomics, deterministic)
// ------------------------------------------------------------------
__global__ void k_rank_count(const double* __restrict__ scores, int* __restrict__ rank) {
  __shared__ double sj[256];
  int i  = blockIdx.x * 256 + threadIdx.x;
  int jb = blockIdx.y * 256;
  sj[threadIdx.x] = scores[jb + threadIdx.x];
  __syncthreads();
  double si = scores[i];
  int cnt = 0;
  for (int t = 0; t < 256; ++t) {
    double s = sj[t];
    int j = jb + t;
    cnt += (int)((s > si) || (s == si && j < i));
  }
  if (cnt) atomicAdd(&rank[i], cnt);
}

__global__ void k_scatter(const double* __restrict__ scores, const double* __restrict__ boxes,
                          const int* __restrict__ rank,
                          double* __restrict__ scores_s, double* __restrict__ boxes_s) {
  int i = blockIdx.x * 256 + threadIdx.x;
  int r = rank[i];
  scores_s[r] = scores[i];
  boxes_s[r * 4 + 0] = boxes[i * 4 + 0];
  boxes_s[r * 4 + 1] = boxes[i * 4 + 1];
  boxes_s[r * 4 + 2] = boxes[i * 4 + 2];
  boxes_s[r * 4 + 3] = boxes[i * 4 + 3];
}

// ------------------------------------------------------------------
// K6: suppression bitmask. fp32 fast-path IoU with fp64 exact fallback
// when |inter-0.5*uni| <= 1e-3*uni (fp32 error ~1e-6*uni). Skips whole
// words <= i.
// ------------------------------------------------------------------
__global__ void k_mask(const double* __restrict__ boxes_s, unsigned long long* __restrict__ mask) {
  __shared__ float jb[256][4];
  __shared__ float ib[64][4];
  const int tid = threadIdx.x;
  const int j0 = blockIdx.x * 256;
  const int i0 = blockIdx.y * 64;
  for (int idx = tid; idx < 1024; idx += 256) jb[idx >> 2][idx & 3] = (float)boxes_s[j0 * 4 + idx];
  for (int idx = tid; idx < 256; idx += 256) ib[idx >> 2][idx & 3] = (float)boxes_s[i0 * 4 + idx];
  __syncthreads();
  const int il = tid >> 2;
  const int i  = i0 + il;
  const int wq = blockIdx.x * 4 + (tid & 3);
  const int jlb = (tid & 3) * 64;
  unsigned long long m = 0ull;
  if (wq * 64 + 63 > i) {
    const float ix1 = ib[il][0], iy1 = ib[il][1], ix2 = ib[il][2], iy2 = ib[il][3];
    const float iarea = (ix2 - ix1) * (iy2 - iy1);
    for (int b = 0; b < 64; ++b) {
      const int j = wq * 64 + b;
      const float jx1 = jb[jlb + b][0], jy1 = jb[jlb + b][1];
      const float jx2 = jb[jlb + b][2], jy2 = jb[jlb + b][3];
      const float xx1 = fmaxf(ix1, jx1), yy1 = fmaxf(iy1, jy1);
      const float xx2 = fminf(ix2, jx2), yy2 = fminf(iy2, jy2);
      const float iw = fmaxf(xx2 - xx1, 0.f), ih = fmaxf(yy2 - yy1, 0.f);
      const float inter = iw * ih;
      const float jarea = (jx2 - jx1) * (jy2 - jy1);
      const float uni = fmaxf(iarea + jarea - inter, 1e-9f);
      const float diff = inter - 0.5f * uni;
      bool sup;
      if (fabsf(diff) <= 1e-3f * uni) {
        const double dix1 = boxes_s[(size_t)i * 4 + 0], diy1 = boxes_s[(size_t)i * 4 + 1];
        const double dix2 = boxes_s[(size_t)i * 4 + 2], diy2 = boxes_s[(size_t)i * 4 + 3];
        const double djx1 = boxes_s[(size_t)j * 4 + 0], djy1 = boxes_s[(size_t)j * 4 + 1];
        const double djx2 = boxes_s[(size_t)j * 4 + 2], djy2 = boxes_s[(size_t)j * 4 + 3];
        const double dxx1 = fmax(dix1, djx1), dyy1 = fmax(diy1, djy1);
        const double dxx2 = fmin(dix2, djx2), dyy2 = fmin(diy2, djy2);
        const double diw = fmax(dxx2 - dxx1, 0.0), dih = fmax(dyy2 - dyy1, 0.0);
        const double dinter = diw * dih;
        const double dia = (dix2 - dix1) * (diy2 - diy1);
        const double dja = (djx2 - djx1) * (djy2 - djy1);
        const double duni = fmax(dia + dja - dinter, 1e-9);
        sup = dinter > 0.5 * duni;
      } else {
        sup = diff > 0.f;
      }
      if (sup && j > i) m |= (1ull << b);
    }
  }
  mask[(size_t)i * NWRD + wq] = m;
}

// ------------------------------------------------------------------
// K7: greedy scan, single wave, barrier-free (round-10 proven).
// ------------------------------------------------------------------
__global__ void k_nms_scan(const unsigned long long* __restrict__ mask,
                           int* __restrict__ keep) {
  const int l = threadIdx.x & 63;
  unsigned long long r0 = 0ull, r1 = 0ull, r2 = (l < 16) ? 0ull : ~0ull;
  const int w0 = l, w1 = l + 64, w2 = l + 128;
  int prev = -1;
  while (true) {
    int cand = 1 << 30;
    unsigned long long b;
    b = ~r0;
    if (w0 * 64 <= prev) b = (w0 * 64 + 63 <= prev) ? 0ull : (b & (~0ull << (prev + 1 - w0 * 64)));
    if (b) cand = w0 * 64 + __ffsll((long long)b) - 1;
    b = ~r1;
    if (w1 * 64 <= prev) b = (w1 * 64 + 63 <= prev) ? 0ull : (b & (~0ull << (prev + 1 - w1 * 64)));
    if (b) { int c = w1 * 64 + __ffsll((long long)b) - 1; cand = c < cand ? c : cand; }
    b = ~r2;
    if (w2 * 64 <= prev) b = (w2 * 64 + 63 <= prev) ? 0ull : (b & (~0ull << (prev + 1 - w2 * 64)));
    if (b) { int c = w2 * 64 + __ffsll((long long)b) - 1; cand = c < cand ? c : cand; }
#pragma unroll
    for (int off = 32; off; off >>= 1) {
      int o = __shfl_xor(cand, off);
      cand = o < cand ? o : cand;
    }
    if (cand >= NBOX) break;
    const int i = cand;
    if (l == 0) keep[i] = 1;
    r0 |= mask[(size_t)i * NWRD + w0];
    r1 |= mask[(size_t)i * NWRD + w1];
    if (l < 16) r2 |= mask[(size_t)i * NWRD + w2];
    prev = i;
  }
}

// ------------------------------------------------------------------
// K8: finalize output (fp32): boxes [9216,4] then scores [9216]
// ------------------------------------------------------------------
__global__ void k_finalize(const double* __restrict__ boxes_s, const double* __restrict__ scores_s,
                           const int* __restrict__ keep, float* __restrict__ out) {
  int r = blockIdx.x * 256 + threadIdx.x;
  int k = keep[r];
  out[r * 4 + 0] = k ? (float)boxes_s[r * 4 + 0] : 0.f;
  out[r * 4 + 1] = k ? (float)boxes_s[r * 4 + 1] : 0.f;
  out[r * 4 + 2] = k ? (float)boxes_s[r * 4 + 2] : 0.f;
  out[r * 4 + 3] = k ? (float)boxes_s[r * 4 + 3] : 0.f;
  out[NBOX * 4 + r] = k ? (float)scores_s[r] : 0.f;
}

// ------------------------------------------------------------------
static inline size_t alignup(size_t v, size_t a) { return (v + a - 1) & ~(a - 1); }

extern "C" void kernel_launch(void* const* d_in, const int* in_sizes, int n_in,
                              void* d_out, int out_size, void* d_ws, size_t ws_size,
                              hipStream_t stream) {
  const float* x      = (const float*)d_in[0];
  const float* conv_w = (const float*)d_in[1];
  const float* conv_b = (const float*)d_in[2];
  const float* cls_w  = (const float*)d_in[3];
  const float* cls_b  = (const float*)d_in[4];
  const float* bbox_w = (const float*)d_in[5];
  const float* bbox_b = (const float*)d_in[6];
  float* out = (float*)d_out;

  // workspace layout
  char* ws = (char*)d_ws;
  size_t off = 0;
  int* flag = (int*)(ws + off); off = alignup(off + 256, 256);
  unsigned long long* mask = (unsigned long long*)(ws + off); off = alignup(off + (size_t)NBOX * NWRD * 8, 256);
  double* feat     = (double*)(ws + off); off = alignup(off + (size_t)CMID * NPX * 8, 256);
  double* logits   = (double*)(ws + off); off = alignup(off + (size_t)54 * NPX * 8, 256);
  double* scores   = (double*)(ws + off); off = alignup(off + (size_t)NBOX * 8, 256);
  double* boxes    = (double*)(ws + off); off = alignup(off + (size_t)NBOX * 32, 256);
  double* scores_s = (double*)(ws + off); off = alignup(off + (size_t)NBOX * 8, 256);
  double* boxes_s  = (double*)(ws + off); off = alignup(off + (size_t)NBOX * 32, 256);
  int*   rank      = (int*)(ws + off);    off = alignup(off + (size_t)NBOX * 4, 256);
  int*   keep      = (int*)(ws + off);    off = alignup(off + (size_t)NBOX * 4, 256);
  size_t fixed = off;

  // split-K factor: S=8 -> 1024 blocks
  int S = 8;
  while (S > 1 && fixed + (size_t)S * CMID * NPX * 8 > ws_size) S >>= 1;
  double* partial = (double*)(ws + fixed);

  const int chunk = CIN / S;
  const int nblk = 16 * 8 * S;     // always divisible by 8

  hipLaunchKernelGGL(k_probe, dim3(1), dim3(64), 0, stream, flag);
  hipLaunchKernelGGL(k_conv3x3_mfma, dim3(nblk), dim3(256), 0, stream,
                     x, conv_w, partial, chunk, nblk, flag);
  hipLaunchKernelGGL(k_conv3x3_valu, dim3(nblk), dim3(256), 0, stream,
                     x, conv_w, partial, chunk, nblk, flag);
  hipLaunchKernelGGL(k_reduce, dim3((CMID * NPX) / 256), dim3(256), 0, stream,
                     partial, conv_b, feat, S);
  hipLaunchKernelGGL(k_1x1, dim3(4, 6), dim3(256), 0, stream,
                     feat, cls_w, cls_b, bbox_w, bbox_b, logits);
  hipLaunchKernelGGL(k_score_box, dim3(NBOX / 256), dim3(256), 0, stream,
                     logits, scores, boxes, rank, keep);
  hipLaunchKernelGGL(k_rank_count, dim3(36, 36), dim3(256), 0, stream, scores, rank);
  hipLaunchKernelGGL(k_scatter, dim3(NBOX / 256), dim3(256), 0, stream,
                     scores, boxes, rank, scores_s, boxes_s);
  hipLaunchKernelGGL(k_mask, dim3(36, 144), dim3(256), 0, stream, boxes_s, mask);
  hipLaunchKernelGGL(k_nms_scan, dim3(1), dim3(64), 0, stream, mask, keep);
  hipLaunchKernelGGL(k_finalize, dim3(NBOX / 256), dim3(256), 0, stream,
                     boxes_s, scores_s, keep, out);
}

// Round 15
// 532.767 us; speedup vs baseline: 1.1599x; 1.1599x over previous
//
#include <hip/hip_runtime.h>
#include <cstdint>
#include <cmath>

#define HH 32
#define WW 32
#define NPX 1024          // H*W
#define CIN 2048
#define CMID 512
#define NA 9
#define NBOX 9216         // NA*NPX
#define NWRD 144          // NBOX/64

typedef double f64x4 __attribute__((ext_vector_type(4)));

// Device-pass-only builtin resolution (host pass has no amdgcn builtins).
#if defined(__HIP_DEVICE_COMPILE__)
#if __has_builtin(__builtin_amdgcn_mfma_f64_16x16x4f64)
#define MFMA64(a, b, c) __builtin_amdgcn_mfma_f64_16x16x4f64((a), (b), (c), 0, 0, 0)
#elif __has_builtin(__builtin_amdgcn_mfma_f64_16x16x4_f64)
#define MFMA64(a, b, c) __builtin_amdgcn_mfma_f64_16x16x4_f64((a), (b), (c), 0, 0, 0)
#endif
#if __has_builtin(__builtin_amdgcn_global_load_lds)
#define HAVE_GLL 1
#endif
#endif

// ------------------------------------------------------------------
// K0: probe f64 MFMA semantics on-device (proven round-5 probe).
// ------------------------------------------------------------------
__global__ void k_probe(int* __restrict__ flag) {
#ifdef MFMA64
  const int lane = threadIdx.x & 63;
  const int q = lane >> 4, n16 = lane & 15;
  f64x4 z = {0.0, 0.0, 0.0, 0.0};
  f64x4 d1 = MFMA64((double)(n16 + 1), (n16 == 0) ? 1.0 : 0.0, z);
  f64x4 d2 = MFMA64(1.0, (double)(n16 + 1), z);
  bool ok0 = true, ok1 = true, ok2 = true, ok3 = true;
#pragma unroll
  for (int r = 0; r < 4; ++r) {
    const double rc = (double)(4 * q + r + 1);
    const double rs = (double)(q + 4 * r + 1);
    const double p1 = d1[r], p2 = d2[r];
    const double colv = 4.0 * (double)(n16 + 1);
    ok0 &= (p1 == ((n16 == 0) ? 4.0 * rc : 0.0)) && (p2 == colv);
    ok1 &= (p1 == ((n16 == 0) ? 4.0 * rs : 0.0)) && (p2 == colv);
    ok2 &= (p1 == ((4 * q + r == 0) ? colv : 0.0)) && (p2 == 4.0 * rc);
    ok3 &= (p1 == ((q + 4 * r == 0) ? colv : 0.0)) && (p2 == 4.0 * rs);
  }
  const unsigned long long full = ~0ull;
  int f = 0;
  if (__ballot(ok0) == full) f = 1;
  else if (__ballot(ok1) == full) f = 2;
  else if (__ballot(ok2) == full) f = 3;
  else if (__ballot(ok3) == full) f = 4;
  if (threadIdx.x == 0) *flag = f;
#else
  if (threadIdx.x == 0) *flag = 0;
#endif
}

// ------------------------------------------------------------------
// K1a: fp64-MFMA 3x3 conv (runs iff flag != 0). ROUND-13 EXACT BODY
// (best measured: 371us, MfmaUtil 70.5%): gll weights into linear LDS,
// reg-staged fp64 xs, 1 barrier/stage, XCD-aware bijective swizzle,
// launch_bounds(256,2) -> 2 blocks/CU (3 thrashes L2, r12).
// ------------------------------------------------------------------
__global__ __launch_bounds__(256, 2) void k_conv3x3_mfma(
    const float* __restrict__ x, const float* __restrict__ wgt,
    double* __restrict__ partial, int chunk, int nblk,
    const int* __restrict__ flag) {
#ifdef MFMA64
  const int f = *flag;
  if (f == 0) return;
  const bool swp = (f >= 3);
  const bool contig = (f == 1) || (f == 3);

  __shared__ double xs[2][8 * 153];   // [buf][cc*153 + r*38 + lcol]  19584 B
  __shared__ float  wsm[2][4608];     // [buf][oc_l*72 + cc*9 + tap]  36864 B
  const int tid = threadIdx.x;
  // XCD-aware bijective swizzle (nblk % 8 == 0 by construction)
  const int bid = blockIdx.x;
  const int cpx = nblk >> 3;
  const int swz = (bid & 7) * cpx + (bid >> 3);
  const int pxt = swz & 15;          // 0..15
  const int oct = (swz >> 4) & 7;    // 0..7
  const int cz  = swz >> 7;
  const int h0  = pxt * 2;
  const int oc0 = oct * 64;
  const int cbase = cz * chunk;

  const int wv   = tid >> 6;         // wave 0..3
  const int lane = tid & 63;
  const int q    = lane >> 4;        // lane quarter (k offset within K=4)
  const int n16  = lane & 15;

  f64x4 acc[4];
#pragma unroll
  for (int t = 0; t < 4; ++t) acc[t] = (f64x4){0.0, 0.0, 0.0, 0.0};

  float xreg[5];                      // x prefetch (static indices)

#ifdef HAVE_GLL
  int wsrc[5];
#pragma unroll
  for (int m = 0; m < 5; ++m) {
    const int k = wv + 4 * m;                  // chunk id (wave-uniform)
    const int fidx = k * 256 + lane * 4;       // linear float idx in stage
    const int oc_l = fidx / 72;
    const int rem  = fidx - oc_l * 72;
    wsrc[m] = (oc0 + oc_l) * 18432 + rem;
  }
#define WISSUE(P, C0)                                                          \
  _Pragma("unroll")                                                            \
  for (int m = 0; m < 5; ++m) {                                                \
    const int k = wv + 4 * m;                                                  \
    if (k < 18) {                                                              \
      __builtin_amdgcn_global_load_lds(                                        \
          (const __attribute__((address_space(1))) void*)(wgt + (size_t)wsrc[m] + (size_t)(C0) * 9), \
          (__attribute__((address_space(3))) void*)(&wsm[P][k * 256]),         \
          16, 0, 0);                                                           \
    }                                                                          \
  }
#define WCOMMIT(P)
#else
  float wreg[18];
#define WISSUE(P, C0)                                                          \
  _Pragma("unroll")                                                            \
  for (int k = 0; k < 18; ++k) {                                               \
    const int idx = tid + k * 256;                                             \
    const int oc_l = idx / 72, rem = idx - oc_l * 72;                          \
    wreg[k] = wgt[(size_t)(oc0 + oc_l) * 18432 + (size_t)(C0) * 9 + rem];      \
  }
#define WCOMMIT(P)                                                             \
  _Pragma("unroll")                                                            \
  for (int k = 0; k < 18; ++k) wsm[P][tid + k * 256] = wreg[k];
#endif

#define XLOAD(C0)                                                              \
  _Pragma("unroll")                                                            \
  for (int k = 0; k < 5; ++k) {                                                \
    const int idx = tid + k * 256;                                             \
    float v = 0.f;                                                             \
    if (idx < 1152) {                                                          \
      const int cc = idx / 144, rem = idx - cc * 144;                          \
      const int r = rem / 36, lcol = rem - r * 36;                             \
      const int grow = h0 - 1 + r, gcol = lcol - 1;                            \
      if ((unsigned)grow < 32u && (unsigned)gcol < 32u)                        \
        v = x[((size_t)((C0) + cc) << 10) + (grow << 5) + gcol];               \
    }                                                                          \
    xreg[k] = v;                                                               \
  }

#define XWRITE(P)                                                              \
  _Pragma("unroll")                                                            \
  for (int k = 0; k < 5; ++k) {                                                \
    const int idx = tid + k * 256;                                             \
    if (idx < 1152) {                                                          \
      const int cc = idx / 144, rem = idx - cc * 144;                          \
      const int r = rem / 36, lcol = rem - r * 36;                             \
      xs[P][cc * 153 + r * 38 + lcol] = (double)xreg[k];                       \
    }                                                                          \
  }

  const int nst = chunk >> 3;
  WISSUE(0, cbase)
  XLOAD(cbase)
  XWRITE(0)                           // vmcnt drains here
  WCOMMIT(0)
  __syncthreads();

  for (int s = 0; s < nst; ++s) {
    const int p = s & 1;
    if (s + 1 < nst) {
      WISSUE(p ^ 1, cbase + (s + 1) * 8)
      XLOAD(cbase + (s + 1) * 8)
    }
    __builtin_amdgcn_sched_barrier(0);  // keep load-issue ahead of compute

    const double* xb  = &xs[p][q * 153 + n16];
    const float*  wbq = &wsm[p][((wv << 4) + n16) * 72 + q * 9];

#define CONV_INNER(SWPV)                                                       \
    _Pragma("unroll")                                                          \
    for (int tap = 0; tap < 9; ++tap) {                                        \
      const int dy = tap / 3, dx = tap - 3 * (tap / 3);                        \
      _Pragma("unroll")                                                        \
      for (int ksg = 0; ksg < 2; ++ksg) {                                      \
        const double av = (double)wbq[ksg * 36 + tap];                         \
        const double* xq = xb + ksg * 612;   /* 4 ch * 153 */                  \
        _Pragma("unroll")                                                      \
        for (int t = 0; t < 4; ++t) {                                          \
          const double bv = xq[((t >> 1) + dy) * 38 + (t & 1) * 16 + dx];      \
          if (SWPV) acc[t] = MFMA64(bv, av, acc[t]);                           \
          else      acc[t] = MFMA64(av, bv, acc[t]);                           \
        }                                                                      \
      }                                                                        \
    }

    if (swp) { CONV_INNER(true) } else { CONV_INNER(false) }
#undef CONV_INNER

    if (s + 1 < nst) {
      XWRITE(p ^ 1)                   // vmcnt already drained by compute span
      WCOMMIT(p ^ 1)
      __syncthreads();                // single barrier per stage
    }
  }
#undef WISSUE
#undef WCOMMIT
#undef XLOAD
#undef XWRITE
  // epilogue: col = n16 (px within 16-group); row = contig ? 4q+j : q+4j
  double* out = partial + (size_t)cz * (CMID * NPX);
#pragma unroll
  for (int t = 0; t < 4; ++t) {
    const int px = ((h0 + (t >> 1)) << 5) + ((t & 1) << 4) + n16;
#pragma unroll
    for (int j = 0; j < 4; ++j) {
      const int row = contig ? ((q << 2) + j) : (q + (j << 2));
      const int oc = oc0 + (wv << 4) + row;
      out[(size_t)oc * NPX + px] = acc[t][j];
    }
  }
#endif
}

// ------------------------------------------------------------------
// K1b: proven fp64 VALU conv (runs iff flag == 0). Flat grid, same decode.
// ------------------------------------------------------------------
__global__ __launch_bounds__(256) void k_conv3x3_valu(
    const float* __restrict__ x, const float* __restrict__ wgt,
    double* __restrict__ partial, int chunk, int nblk,
    const int* __restrict__ flag) {
  if (*flag != 0) return;
  __shared__ double xs[8][4][36];
  __shared__ double ws_s[8 * 9 * 66];
  const int tid = threadIdx.x;
  const int bid = blockIdx.x;
  const int cpx = nblk >> 3;
  const int swz = (bid & 7) * cpx + (bid >> 3);
  const int pxt = swz & 15;
  const int oct = (swz >> 4) & 7;
  const int cz  = swz >> 7;
  const int h0  = pxt * 2;
  const int oc0 = oct * 64;
  const int cbase = cz * chunk;

  const int g   = tid & 15;
  const int ty  = tid >> 4;
  const int r_p = g >> 3;
  const int gc  = (g & 7) * 4;

  double acc[4][4];
#pragma unroll
  for (int a = 0; a < 4; ++a)
#pragma unroll
    for (int b = 0; b < 4; ++b) acc[a][b] = 0.0;

  const int stages = chunk >> 3;
  for (int s = 0; s < stages; ++s) {
    const int c0 = cbase + s * 8;
    __syncthreads();
    for (int idx = tid; idx < 1152; idx += 256) {
      int cc = idx / 144, rem = idx - cc * 144;
      int r = rem / 36, lcol = rem - r * 36;
      int grow = h0 - 1 + r, gcol = lcol - 1;
      float v = 0.f;
      if ((unsigned)grow < 32u && (unsigned)gcol < 32u)
        v = x[((size_t)(c0 + cc) << 10) + (grow << 5) + gcol];
      xs[cc][r][lcol] = (double)v;
    }
    for (int idx = tid; idx < 4608; idx += 256) {
      int oc_l = idx / 72, rem = idx - oc_l * 72;
      int cc = rem / 9, t = rem - cc * 9;
      ws_s[(cc * 9 + t) * 66 + oc_l] =
          (double)wgt[(size_t)(oc0 + oc_l) * 18432 + (size_t)(c0 + cc) * 9 + t];
    }
    __syncthreads();
    for (int cc = 0; cc < 8; ++cc) {
      double xr[3][8];
#pragma unroll
      for (int dy = 0; dy < 3; ++dy) {
        const double* xp = &xs[cc][r_p + dy][gc];
#pragma unroll
        for (int k = 0; k < 8; ++k) xr[dy][k] = xp[k];
      }
#pragma unroll
      for (int t = 0; t < 9; ++t) {
        const int dy = t / 3, dx = t - dy * 3;
        const double* wp = &ws_s[(cc * 9 + t) * 66 + ty * 4];
        const double w0 = wp[0], w1 = wp[1], w2 = wp[2], w3 = wp[3];
#pragma unroll
        for (int i = 0; i < 4; ++i) {
          const double xv = xr[dy][i + dx];
          acc[0][i] += w0 * xv;
          acc[1][i] += w1 * xv;
          acc[2][i] += w2 * xv;
          acc[3][i] += w3 * xv;
        }
      }
    }
  }
  const int pxg = (h0 + r_p) * 32 + gc;
  double* out = partial + (size_t)cz * (CMID * NPX);
#pragma unroll
  for (int j = 0; j < 4; ++j)
#pragma unroll
    for (int i = 0; i < 4; ++i)
      out[(size_t)(oc0 + ty * 4 + j) * NPX + pxg + i] = acc[j][i];
}

// ------------------------------------------------------------------
// K2: reduce split-K partials + bias + ReLU (fp64), double2-vectorized.
// idx even -> both elements share oc; per-element z-order unchanged ->
// bitwise identical to the scalar version.
// ------------------------------------------------------------------
__global__ void k_reduce(const double* __restrict__ partial,
                         const float* __restrict__ bias,
                         double* __restrict__ feat, int S) {
  int idx = (blockIdx.x * 256 + threadIdx.x) * 2;   // < 512*1024
  double b = (double)bias[idx >> 10];
  double s0 = b, s1 = b;
  for (int z = 0; z < S; ++z) {
    const double2 p = *(const double2*)&partial[(size_t)z * (CMID * NPX) + idx];
    s0 += p.x; s1 += p.y;
  }
  double2 r; r.x = fmax(s0, 0.0); r.y = fmax(s1, 0.0);
  *(double2*)&feat[idx] = r;
}

// ------------------------------------------------------------------
// K3: 1x1 convs (cls 18ch + bbox 36ch), fp64 scalar dot.
// grid (4 px-blocks, 54 channels) = 216 blocks (round-10 proven config;
// the 24-block LDS variant under-occupied and cost ~60-70us of tail).
// ------------------------------------------------------------------
__global__ void k_1x1(const double* __restrict__ feat,
                      const float* __restrict__ cls_w, const float* __restrict__ cls_b,
                      const float* __restrict__ bbox_w, const float* __restrict__ bbox_b,
                      double* __restrict__ logits) {
  int px = blockIdx.x * 256 + threadIdx.x;
  int ch = blockIdx.y;
  const float* wv;
  float bias;
  if (ch < 18) { wv = cls_w + (size_t)ch * 512; bias = cls_b[ch]; }
  else         { wv = bbox_w + (size_t)(ch - 18) * 512; bias = bbox_b[ch - 18]; }
  double acc = 0.0;
  for (int c = 0; c < 512; ++c)
    acc += feat[((size_t)c << 10) + px] * (double)wv[c];
  logits[((size_t)ch << 10) + px] = acc + (double)bias;
}

// ------------------------------------------------------------------
// K4: scores (fp64 sigmoid) + box decode (fp64) + rank/keep zero-init
// ------------------------------------------------------------------
__global__ void k_score_box(const double* __restrict__ logits,
                            double* __restrict__ scores, double* __restrict__ boxes,
                            int* __restrict__ rank, int* __restrict__ keep) {
  int i = blockIdx.x * 256 + threadIdx.x;     // < 9216
  rank[i] = 0;
  keep[i] = 0;
  int pos = i / 9, a = i - pos * 9;
  const double* obj = logits;
  const double* dl  = logits + 18 * NPX;
  double l0 = obj[a * NPX + pos], l1 = obj[(9 + a) * NPX + pos];
  double delta = l1 - l0;
  scores[i] = 1.0 / (1.0 + exp(-delta));
  double d0 = dl[(a * 4 + 0) * NPX + pos], d1 = dl[(a * 4 + 1) * NPX + pos];
  double d2 = dl[(a * 4 + 2) * NPX + pos], d3 = dl[(a * 4 + 3) * NPX + pos];
  const double s_arr[3] = {8.0, 16.0, 32.0};
  const double r_arr[3] = {0.5, 1.0, 2.0};
  double sA = s_arr[a / 3], rA = r_arr[a % 3];
  double aw = (double)(float)(sA * sqrt(rA));
  double ah = (double)(float)(sA / sqrt(rA));
  double px_ = d0 * aw, py_ = d1 * ah;
  double pw = exp(d2) * aw, ph = exp(d3) * ah;
  boxes[i * 4 + 0] = px_ - 0.5 * pw;
  boxes[i * 4 + 1] = py_ - 0.5 * ph;
  boxes[i * 4 + 2] = px_ + 0.5 * pw;
  boxes[i * 4 + 3] = py_ + 0.5 * ph;
}

// ------------------------------------------------------------------
// K5: stable descending rank via O(N^2) count (int atomics, deterministic)
// ------------------------------------------------------------------
__global__ void k_rank_count(const double* __restrict__ scores, int* __restrict__ rank) {
  __shared__ double sj[256];
  int i  = blockIdx.x * 256 + threadIdx.x;
  int jb = blockIdx.y * 256;
  sj[threadIdx.x] = scores[jb + threadIdx.x];
  __syncthreads();
  double si = scores[i];
  int cnt = 0;
  for (int t = 0; t < 256; ++t) {
    double s = sj[t];
    int j = jb + t;
    cnt += (int)((s > si) || (s == si && j < i));
  }
  if (cnt) atomicAdd(&rank[i], cnt);
}

__global__ void k_scatter(const double* __restrict__ scores, const double* __restrict__ boxes,
                          const int* __restrict__ rank,
                          double* __restrict__ scores_s, double* __restrict__ boxes_s) {
  int i = blockIdx.x * 256 + threadIdx.x;
  int r = rank[i];
  scores_s[r] = scores[i];
  boxes_s[r * 4 + 0] = boxes[i * 4 + 0];
  boxes_s[r * 4 + 1] = boxes[i * 4 + 1];
  boxes_s[r * 4 + 2] = boxes[i * 4 + 2];
  boxes_s[r * 4 + 3] = boxes[i * 4 + 3];
}

// ------------------------------------------------------------------
// K6: suppression bitmask. fp32 fast-path IoU with fp64 exact fallback
// when |inter-0.5*uni| <= 1e-3*uni (fp32 error ~1e-6*uni). Skips whole
// words <= i.
// ------------------------------------------------------------------
__global__ void k_mask(const double* __restrict__ boxes_s, unsigned long long* __restrict__ mask) {
  __shared__ float jb[256][4];
  __shared__ float ib[64][4];
  const int tid = threadIdx.x;
  const int j0 = blockIdx.x * 256;
  const int i0 = blockIdx.y * 64;
  for (int idx = tid; idx < 1024; idx += 256) jb[idx >> 2][idx & 3] = (float)boxes_s[j0 * 4 + idx];
  for (int idx = tid; idx < 256; idx += 256) ib[idx >> 2][idx & 3] = (float)boxes_s[i0 * 4 + idx];
  __syncthreads();
  const int il = tid >> 2;
  const int i  = i0 + il;
  const int wq = blockIdx.x * 4 + (tid & 3);
  const int jlb = (tid & 3) * 64;
  unsigned long long m = 0ull;
  if (wq * 64 + 63 > i) {
    const float ix1 = ib[il][0], iy1 = ib[il][1], ix2 = ib[il][2], iy2 = ib[il][3];
    const float iarea = (ix2 - ix1) * (iy2 - iy1);
    for (int b = 0; b < 64; ++b) {
      const int j = wq * 64 + b;
      const float jx1 = jb[jlb + b][0], jy1 = jb[jlb + b][1];
      const float jx2 = jb[jlb + b][2], jy2 = jb[jlb + b][3];
      const float xx1 = fmaxf(ix1, jx1), yy1 = fmaxf(iy1, jy1);
      const float xx2 = fminf(ix2, jx2), yy2 = fminf(iy2, jy2);
      const float iw = fmaxf(xx2 - xx1, 0.f), ih = fmaxf(yy2 - yy1, 0.f);
      const float inter = iw * ih;
      const float jarea = (jx2 - jx1) * (jy2 - jy1);
      const float uni = fmaxf(iarea + jarea - inter, 1e-9f);
      const float diff = inter - 0.5f * uni;
      bool sup;
      if (fabsf(diff) <= 1e-3f * uni) {
        const double dix1 = boxes_s[(size_t)i * 4 + 0], diy1 = boxes_s[(size_t)i * 4 + 1];
        const double dix2 = boxes_s[(size_t)i * 4 + 2], diy2 = boxes_s[(size_t)i * 4 + 3];
        const double djx1 = boxes_s[(size_t)j * 4 + 0], djy1 = boxes_s[(size_t)j * 4 + 1];
        const double djx2 = boxes_s[(size_t)j * 4 + 2], djy2 = boxes_s[(size_t)j * 4 + 3];
        const double dxx1 = fmax(dix1, djx1), dyy1 = fmax(diy1, djy1);
        const double dxx2 = fmin(dix2, djx2), dyy2 = fmin(diy2, djy2);
        const double diw = fmax(dxx2 - dxx1, 0.0), dih = fmax(dyy2 - dyy1, 0.0);
        const double dinter = diw * dih;
        const double dia = (dix2 - dix1) * (diy2 - diy1);
        const double dja = (djx2 - djx1) * (djy2 - djy1);
        const double duni = fmax(dia + dja - dinter, 1e-9);
        sup = dinter > 0.5 * duni;
      } else {
        sup = diff > 0.f;
      }
      if (sup && j > i) m |= (1ull << b);
    }
  }
  mask[(size_t)i * NWRD + wq] = m;
}

// ------------------------------------------------------------------
// K7: greedy scan, single wave, barrier-free (round-10 proven).
// ------------------------------------------------------------------
__global__ void k_nms_scan(const unsigned long long* __restrict__ mask,
                           int* __restrict__ keep) {
  const int l = threadIdx.x & 63;
  unsigned long long r0 = 0ull, r1 = 0ull, r2 = (l < 16) ? 0ull : ~0ull;
  const int w0 = l, w1 = l + 64, w2 = l + 128;
  int prev = -1;
  while (true) {
    int cand = 1 << 30;
    unsigned long long b;
    b = ~r0;
    if (w0 * 64 <= prev) b = (w0 * 64 + 63 <= prev) ? 0ull : (b & (~0ull << (prev + 1 - w0 * 64)));
    if (b) cand = w0 * 64 + __ffsll((long long)b) - 1;
    b = ~r1;
    if (w1 * 64 <= prev) b = (w1 * 64 + 63 <= prev) ? 0ull : (b & (~0ull << (prev + 1 - w1 * 64)));
    if (b) { int c = w1 * 64 + __ffsll((long long)b) - 1; cand = c < cand ? c : cand; }
    b = ~r2;
    if (w2 * 64 <= prev) b = (w2 * 64 + 63 <= prev) ? 0ull : (b & (~0ull << (prev + 1 - w2 * 64)));
    if (b) { int c = w2 * 64 + __ffsll((long long)b) - 1; cand = c < cand ? c : cand; }
#pragma unroll
    for (int off = 32; off; off >>= 1) {
      int o = __shfl_xor(cand, off);
      cand = o < cand ? o : cand;
    }
    if (cand >= NBOX) break;
    const int i = cand;
    if (l == 0) keep[i] = 1;
    r0 |= mask[(size_t)i * NWRD + w0];
    r1 |= mask[(size_t)i * NWRD + w1];
    if (l < 16) r2 |= mask[(size_t)i * NWRD + w2];
    prev = i;
  }
}

// ------------------------------------------------------------------
// K8: finalize output (fp32): boxes [9216,4] then scores [9216]
// ------------------------------------------------------------------
__global__ void k_finalize(const double* __restrict__ boxes_s, const double* __restrict__ scores_s,
                           const int* __restrict__ keep, float* __restrict__ out) {
  int r = blockIdx.x * 256 + threadIdx.x;
  int k = keep[r];
  out[r * 4 + 0] = k ? (float)boxes_s[r * 4 + 0] : 0.f;
  out[r * 4 + 1] = k ? (float)boxes_s[r * 4 + 1] : 0.f;
  out[r * 4 + 2] = k ? (float)boxes_s[r * 4 + 2] : 0.f;
  out[r * 4 + 3] = k ? (float)boxes_s[r * 4 + 3] : 0.f;
  out[NBOX * 4 + r] = k ? (float)scores_s[r] : 0.f;
}

// ------------------------------------------------------------------
static inline size_t alignup(size_t v, size_t a) { return (v + a - 1) & ~(a - 1); }

extern "C" void kernel_launch(void* const* d_in, const int* in_sizes, int n_in,
                              void* d_out, int out_size, void* d_ws, size_t ws_size,
                              hipStream_t stream) {
  const float* x      = (const float*)d_in[0];
  const float* conv_w = (const float*)d_in[1];
  const float* conv_b = (const float*)d_in[2];
  const float* cls_w  = (const float*)d_in[3];
  const float* cls_b  = (const float*)d_in[4];
  const float* bbox_w = (const float*)d_in[5];
  const float* bbox_b = (const float*)d_in[6];
  float* out = (float*)d_out;

  // workspace layout
  char* ws = (char*)d_ws;
  size_t off = 0;
  int* flag = (int*)(ws + off); off = alignup(off + 256, 256);
  unsigned long long* mask = (unsigned long long*)(ws + off); off = alignup(off + (size_t)NBOX * NWRD * 8, 256);
  double* feat     = (double*)(ws + off); off = alignup(off + (size_t)CMID * NPX * 8, 256);
  double* logits   = (double*)(ws + off); off = alignup(off + (size_t)54 * NPX * 8, 256);
  double* scores   = (double*)(ws + off); off = alignup(off + (size_t)NBOX * 8, 256);
  double* boxes    = (double*)(ws + off); off = alignup(off + (size_t)NBOX * 32, 256);
  double* scores_s = (double*)(ws + off); off = alignup(off + (size_t)NBOX * 8, 256);
  double* boxes_s  = (double*)(ws + off); off = alignup(off + (size_t)NBOX * 32, 256);
  int*   rank      = (int*)(ws + off);    off = alignup(off + (size_t)NBOX * 4, 256);
  int*   keep      = (int*)(ws + off);    off = alignup(off + (size_t)NBOX * 4, 256);
  size_t fixed = off;

  // split-K factor: S=8 -> 1024 blocks
  int S = 8;
  while (S > 1 && fixed + (size_t)S * CMID * NPX * 8 > ws_size) S >>= 1;
  double* partial = (double*)(ws + fixed);

  const int chunk = CIN / S;
  const int nblk = 16 * 8 * S;     // always divisible by 8

  hipLaunchKernelGGL(k_probe, dim3(1), dim3(64), 0, stream, flag);
  hipLaunchKernelGGL(k_conv3x3_mfma, dim3(nblk), dim3(256), 0, stream,
                     x, conv_w, partial, chunk, nblk, flag);
  hipLaunchKernelGGL(k_conv3x3_valu, dim3(nblk), dim3(256), 0, stream,
                     x, conv_w, partial, chunk, nblk, flag);
  hipLaunchKernelGGL(k_reduce, dim3((CMID * NPX) / 512), dim3(256), 0, stream,
                     partial, conv_b, feat, S);
  hipLaunchKernelGGL(k_1x1, dim3(4, 54), dim3(256), 0, stream,
                     feat, cls_w, cls_b, bbox_w, bbox_b, logits);
  hipLaunchKernelGGL(k_score_box, dim3(NBOX / 256), dim3(256), 0, stream,
                     logits, scores, boxes, rank, keep);
  hipLaunchKernelGGL(k_rank_count, dim3(36, 36), dim3(256), 0, stream, scores, rank);
  hipLaunchKernelGGL(k_scatter, dim3(NBOX / 256), dim3(256), 0, stream,
                     scores, boxes, rank, scores_s, boxes_s);
  hipLaunchKernelGGL(k_mask, dim3(36, 144), dim3(256), 0, stream, boxes_s, mask);
  hipLaunchKernelGGL(k_nms_scan, dim3(1), dim3(64), 0, stream, mask, keep);
  hipLaunchKernelGGL(k_finalize, dim3(NBOX / 256), dim3(256), 0, stream,
                     boxes_s, scores_s, keep, out);
}